// Round 23
// baseline (163.327 us; speedup 1.0000x reference)
//
#include <hip/hip_runtime.h>
#include <hip/hip_bf16.h>

// B=32, S=2048, D=1024, C=256
//   top[b,s] = max_c sum_d (latent[c,d]*att_diag[d]) * (tm*embeds[b,s,d] + pos_table[rel+64,d])
//   p = softmax_s(top*m + (m-1)*NEG);  ctx[b,d] = tok_diag[d] * sum_s embeds*p
//
// R23 = R20's proven per-wave core (32 tok x 16 ct x 2-term split-fp16,
// e staged via global_load_lds w/ XOR swizzle, pos reg-prefetched),
// repackaged as 64-token / 2-wave blocks (grid 1024):
//   LDS 50KB -> 3 blocks/CU = 3 independent barrier domains (was 2),
//   W LDS read traffic per CU -25%, 2x block count for tail/XCD balance.
// FIFO per iter: consume P(kc) [oldest, auto-wait], issue W(kc+1):8 +
// E(kc+1):4, issue P(kc+1):4, end vmcnt(4) drains W+E only.
//
// ws: whi 512K | partial 4M | mblk 4K | zblk 4K

#define HC 64
#define NEGV 1000000000000.0f

constexpr int Bb = 32, Ss = 2048, Dd = 1024, Cc = 256;
constexpr int NKC = 32;                 // k-chunks of 32
constexpr int CT = Cc / 16;             // 16 c-tiles
constexpr int NBLK = 32;                // 64-token blocks per batch

typedef _Float16 f16x8 __attribute__((ext_vector_type(8)));
typedef float    f32x4 __attribute__((ext_vector_type(4)));

// ---------------- Pass 0: W_hi -> per-kc fragment chunks ----------
// layout: whi[kc][ct][lane][8] (16KB/kc)
// A-frag map: lane = (c%16) + 16*g holds A[c][k = kc*32 + 8g + i]
__global__ __launch_bounds__(256) void k_prep_w(
    const float* __restrict__ latent, const float* __restrict__ att_diag,
    _Float16* __restrict__ whi)
{
    const int idx = blockIdx.x * 256 + threadIdx.x;   // c*Dd + k
    const int c = idx >> 10, k = idx & 1023;
    const float wv = latent[idx] * att_diag[k];
    const int kc = k >> 5, g = (k >> 3) & 3, i = k & 7;
    const int lane = (c & 15) + 16 * g, ct = c >> 4;
    whi[(size_t)kc * 8192 + (size_t)ct * 512 + lane * 8 + i] = (_Float16)wv;
}

// ------- Pass 1: scores via MFMA, block max/sumexp, flash ctx partial -----
__global__ __launch_bounds__(128, 2) void k_scores_mfma(
    const float* __restrict__ embeds,    // [B][S][D]
    const float* __restrict__ mask,      // [B][S]
    const float* __restrict__ pos_table, // [132][D]
    const float* __restrict__ tok_mult,  // [1]
    const int*   __restrict__ rel_ids,   // [B][S]
    const _Float16* __restrict__ whi,    // [NKC][CT][64][8]
    float* __restrict__ partial,         // [B][NBLK][D]
    float* __restrict__ mblk,            // [B][NBLK]
    float* __restrict__ zblk)            // [B][NBLK]
{
    __shared__ _Float16 sbufW[2][8192];  // 2 x 16KB (W_hi chunks)
    __shared__ float    sbufE[2][2048];  // 2 x 8KB (e tiles, swizzled)
    __shared__ float l_sh[64];
    __shared__ float w_sh[64];
    __shared__ float red1[2];

    const int t  = threadIdx.x;
    const int wv = t >> 6;      // wave 0..1
    const int l  = t & 63;
    const int lr = l & 15;      // token within set / output col
    const int lg = l >> 4;      // k-group

    const int b   = blockIdx.x >> 5;     // 32 blocks of 64 tokens per batch
    const int blk = blockIdx.x & 31;
    const int s0  = blk * 64;

    const float tm = tok_mult[0];

    const float* prow[2];
    #pragma unroll
    for (int st = 0; st < 2; st++) {
        const int tok = s0 + wv * 32 + st * 16 + lr;
        prow[st] = pos_table + (size_t)(rel_ids[b * Ss + tok] + HC) * Dd;
    }

    f32x4 acc[CT][2];
    #pragma unroll
    for (int ct = 0; ct < CT; ct++)
        #pragma unroll
        for (int st = 0; st < 2; st++) acc[ct][st] = (f32x4){0.f, 0.f, 0.f, 0.f};

    // pos prefetch registers (one kc ahead): 4 gather loads (cache-hot rows)
    f32x4 p0[2], p1[2];
    auto loadP = [&](int kc) {
        const int k0 = kc * 32 + lg * 8;
        #pragma unroll
        for (int st = 0; st < 2; st++) {
            p0[st] = *(const f32x4*)(prow[st] + k0);
            p1[st] = *(const f32x4*)(prow[st] + k0 + 4);
        }
    };

    // stage one 16KB W_hi chunk: 128 thr x 16B -> 8 insts/thread
    auto stageW = [&](int kc, _Float16* dst) {
        const _Float16* src = whi + (size_t)kc * 8192;
        #pragma unroll
        for (int i = 0; i < 8; i++) {
            const int off = (i * 2 + wv) << 9;   // elems; 1KB chunks
            __builtin_amdgcn_global_load_lds(
                (const __attribute__((address_space(1))) void*)(src + off + l * 8),
                (__attribute__((address_space(3))) void*)(dst + off),
                16, 0, 0);
        }
    };

    // stage one 8KB e tile [64 rows][8 16B-units], XOR-swizzled:
    // LDS unit j = row*8 + u holds e[row][u ^ (row&7)] (16B units).
    auto stageE = [&](int kc, float* dst) {
        const float* ebase = embeds + ((size_t)b * Ss + s0) * Dd + kc * 32;
        #pragma unroll
        for (int i = 0; i < 4; i++) {
            const int jbase = i * 128 + wv * 64;     // unit idx of lane 0
            const int j = jbase + l;                 // this lane's unit
            const int row = j >> 3, u = j & 7;
            const float* src = ebase + (size_t)row * Dd + ((u ^ (row & 7)) << 2);
            __builtin_amdgcn_global_load_lds(
                (const __attribute__((address_space(1))) void*)src,
                (__attribute__((address_space(3))) void*)(dst + jbase * 4),
                16, 0, 0);
        }
    };

    // prologue: queue = [W(0):8, E(0):4, P(0):4]
    stageW(0, sbufW[0]);
    stageE(0, sbufE[0]);
    loadP(0);
    asm volatile("s_waitcnt vmcnt(4)" ::: "memory");  // W(0)+E(0) landed
    __builtin_amdgcn_s_barrier();

    int cur = 0;
    for (int kc = 0; kc < NKC; kc++) {
        if (kc + 1 < NKC) {
            stageW(kc + 1, sbufW[cur ^ 1]);   // 8 DMA
            stageE(kc + 1, sbufE[cur ^ 1]);   // 4 DMA
        }

        // build B frags: e from swizzled LDS, pos from prefetch regs
        // (first use of p regs auto-waits on P(kc), the oldest in queue)
        f16x8 bh[2], bl[2];
        {
            const float* es = sbufE[cur];
            #pragma unroll
            for (int st = 0; st < 2; st++) {
                const int row = wv * 32 + st * 16 + lr;
                const int sw  = row & 7;
                const f32x4 x0 = *(const f32x4*)(es + row * 32 + (((lg << 1)    ) ^ sw) * 4);
                const f32x4 x1 = *(const f32x4*)(es + row * 32 + (((lg << 1) | 1) ^ sw) * 4);
                float e[8], p[8];
                *(f32x4*)&e[0] = x0;     *(f32x4*)&e[4] = x1;
                *(f32x4*)&p[0] = p0[st]; *(f32x4*)&p[4] = p1[st];
                #pragma unroll
                for (int i = 0; i < 8; i++) {
                    const float x = fmaf(tm, e[i], p[i]);
                    const _Float16 h = (_Float16)x;
                    bh[st][i] = h;
                    bl[st][i] = (_Float16)(x - (float)h);
                }
            }
        }
        if (kc + 1 < NKC) loadP(kc + 1);   // 4 gathers; stay in flight

        const _Float16* base = sbufW[cur];
        #pragma unroll
        for (int ct = 0; ct < CT; ct++) {
            const f16x8 ah = *(const f16x8*)(base + ct * 512 + l * 8);
            #pragma unroll
            for (int st = 0; st < 2; st++) {
                acc[ct][st] = __builtin_amdgcn_mfma_f32_16x16x32_f16(ah, bh[st], acc[ct][st], 0, 0, 0);
                acc[ct][st] = __builtin_amdgcn_mfma_f32_16x16x32_f16(ah, bl[st], acc[ct][st], 0, 0, 0);
            }
        }
        // drain this iter's 12 DMA (oldest after P(kc) consumed); P(kc+1) flies
        if (kc + 1 < NKC) { asm volatile("s_waitcnt vmcnt(4)" ::: "memory"); }
        else              { asm volatile("s_waitcnt vmcnt(0)" ::: "memory"); }
        __builtin_amdgcn_s_barrier();
        cur ^= 1;
    }

    // masked logit per token -> LDS
    #pragma unroll
    for (int st = 0; st < 2; st++) {
        float mx = acc[0][st][0];
        #pragma unroll
        for (int ct = 0; ct < CT; ct++)
            #pragma unroll
            for (int r = 0; r < 4; r++) mx = fmaxf(mx, acc[ct][st][r]);
        mx = fmaxf(mx, __shfl_xor(mx, 16));
        mx = fmaxf(mx, __shfl_xor(mx, 32));
        if (lg == 0) {
            const int si = wv * 32 + st * 16 + lr;   // token within block
            const int s  = s0 + si;
            const float mk = mask[b * Ss + s];
            l_sh[si] = mx * mk + (mk - 1.0f) * NEGV;
        }
    }
    __syncthreads();

    // block max M_b and Z_b over the 64 logits (one wave)
    if (t < 64) {
        float v = l_sh[t];
        #pragma unroll
        for (int o = 32; o >= 1; o >>= 1) v = fmaxf(v, __shfl_xor(v, o));
        if (t == 0) red1[0] = v;
    }
    __syncthreads();
    const float Mb = red1[0];
    if (t < 64) {
        const float wgt = expf(l_sh[t] - Mb);
        w_sh[t] = wgt;
        float z = wgt;
        #pragma unroll
        for (int o = 32; o >= 1; o >>= 1) z += __shfl_xor(z, o);
        if (t == 0) red1[1] = z;
    }
    __syncthreads();

    // block-local ctx partial: P[d] = sum_s w_sh[s] * e[s0+s][d]  (L2-hot)
    {
        const float* eb = embeds + ((size_t)b * Ss + s0) * Dd + t * 8;
        f32x4 ca = (f32x4){0.f, 0.f, 0.f, 0.f};
        f32x4 cb = (f32x4){0.f, 0.f, 0.f, 0.f};
        #pragma unroll 4
        for (int s = 0; s < 64; s++) {
            const float wgt = w_sh[s];
            const f32x4 ev = *(const f32x4*)(eb + (size_t)s * Dd);
            const f32x4 ew = *(const f32x4*)(eb + (size_t)s * Dd + 4);
            ca[0] = fmaf(wgt, ev[0], ca[0]);
            ca[1] = fmaf(wgt, ev[1], ca[1]);
            ca[2] = fmaf(wgt, ev[2], ca[2]);
            ca[3] = fmaf(wgt, ev[3], ca[3]);
            cb[0] = fmaf(wgt, ew[0], cb[0]);
            cb[1] = fmaf(wgt, ew[1], cb[1]);
            cb[2] = fmaf(wgt, ew[2], cb[2]);
            cb[3] = fmaf(wgt, ew[3], cb[3]);
        }
        float* pdst = partial + ((size_t)(b * NBLK + blk)) * Dd + t * 8;
        *(f32x4*)(pdst)     = ca;
        *(f32x4*)(pdst + 4) = cb;
        if (t == 0) {
            mblk[b * NBLK + blk] = Mb;
            zblk[b * NBLK + blk] = red1[1];
        }
    }
}

// ------- Pass 2: global flash combine + tok_diag (parallel over d) -------
__global__ __launch_bounds__(256) void k_finish(
    const float* __restrict__ mblk, const float* __restrict__ zblk,
    const float* __restrict__ partial, const float* __restrict__ tok_diag,
    float* __restrict__ out)
{
    __shared__ float cf[NBLK];
    const int b  = blockIdx.x >> 2;      // batch
    const int dq = blockIdx.x & 3;       // d quarter (256 floats)
    const int t  = threadIdx.x;

    if (t < 64) {
        const float mv = (t < NBLK) ? mblk[b * NBLK + t] : -3.4e38f;
        float M = mv;
        #pragma unroll
        for (int o = 32; o >= 1; o >>= 1) M = fmaxf(M, __shfl_xor(M, o));
        const float zv = (t < NBLK) ? zblk[b * NBLK + t] * expf(mv - M) : 0.f;
        float Z = zv;
        #pragma unroll
        for (int o = 32; o >= 1; o >>= 1) Z += __shfl_xor(Z, o);
        if (t < NBLK) cf[t] = expf(mv - M) / Z;
    }
    __syncthreads();

    const int d = dq * 256 + t;          // one float per thread, coalesced
    float a = 0.f;
    #pragma unroll
    for (int j = 0; j < NBLK; j++)
        a = fmaf(cf[j], partial[((size_t)(b * NBLK + j)) * Dd + d], a);
    out[(size_t)b * Dd + d] = a * tok_diag[d];
}

extern "C" void kernel_launch(void* const* d_in, const int* in_sizes, int n_in,
                              void* d_out, int out_size, void* d_ws, size_t ws_size,
                              hipStream_t stream) {
    const float* embeds    = (const float*)d_in[0];
    const float* mask      = (const float*)d_in[1];
    const float* latent    = (const float*)d_in[2];
    const float* att_diag  = (const float*)d_in[3];
    const float* tok_diag  = (const float*)d_in[4];
    const float* pos_table = (const float*)d_in[5];
    const float* tok_mult  = (const float*)d_in[6];
    const int*   rel_ids   = (const int*)d_in[7];
    float* out = (float*)d_out;

    char* ws = (char*)d_ws;
    _Float16* whi    = (_Float16*)(ws);              // 512 KB
    float*    partial= (float*)(ws + 524288);        // 4 MB
    float*    mblk   = (float*)(ws + 4718592);       // 4 KB
    float*    zblk   = (float*)(ws + 4722688);       // 4 KB

    k_prep_w<<<(Cc * Dd) / 256, 256, 0, stream>>>(latent, att_diag, whi);
    k_scores_mfma<<<Bb * NBLK, 128, 0, stream>>>(
        embeds, mask, pos_table, tok_mult, rel_ids, whi, partial, mblk, zblk);
    k_finish<<<Bb * 4, 256, 0, stream>>>(mblk, zblk, partial, tok_diag, out);
}

// Round 24
// 114.324 us; speedup vs baseline: 1.4286x; 1.4286x over previous
//
#include <hip/hip_runtime.h>
#include <hip/hip_bf16.h>

// B=32, S=2048, D=1024, C=256
//   top[b,s] = max_c sum_d (latent[c,d]*att_diag[d]) * (tm*embeds[b,s,d] + pos_table[rel+64,d])
//   p = softmax_s(top*m + (m-1)*NEG);  ctx[b,d] = tok_diag[d] * sum_s embeds*p
//
// R24 = R22 (best, 113.3us: e via global_load_lds, 3-deep e-ring, 80KB LDS)
// + two zero-cost scheduling tweaks:
//  1) MFMA dep-break: inner burst reordered (hi,st0)(hi,st1)(lo,st0)(lo,st1)
//     -> same-acc MFMA dep distance 1 -> 2 (hi->lo pairs were back-to-back).
//  2) s_setprio(1/0) around the MFMA burst (T5; multi-gang role diversity).
// Everything else identical to R22.
//
// ws: whi 512K | partial 2M | mblk 2K | zblk 2K

#define HC 64
#define NEGV 1000000000000.0f

constexpr int Bb = 32, Ss = 2048, Dd = 1024, Cc = 256;
constexpr int NKC = 32;                 // k-chunks of 32
constexpr int CT = Cc / 16;             // 16 c-tiles
constexpr int NBLK = 16;                // 128-token blocks per batch

typedef _Float16 f16x8 __attribute__((ext_vector_type(8)));
typedef float    f32x4 __attribute__((ext_vector_type(4)));

// ---------------- Pass 0: W_hi -> per-kc fragment chunks ----------
// layout: whi[kc][ct][lane][8] (16KB/kc)
// A-frag map: lane = (c%16) + 16*g holds A[c][k = kc*32 + 8g + i]
__global__ __launch_bounds__(256) void k_prep_w(
    const float* __restrict__ latent, const float* __restrict__ att_diag,
    _Float16* __restrict__ whi)
{
    const int idx = blockIdx.x * 256 + threadIdx.x;   // c*Dd + k
    const int c = idx >> 10, k = idx & 1023;
    const float wv = latent[idx] * att_diag[k];
    const int kc = k >> 5, g = (k >> 3) & 3, i = k & 7;
    const int lane = (c & 15) + 16 * g, ct = c >> 4;
    whi[(size_t)kc * 8192 + (size_t)ct * 512 + lane * 8 + i] = (_Float16)wv;
}

// ------- Pass 1: scores via MFMA, block max/sumexp, flash ctx partial -----
__global__ __launch_bounds__(256, 2) void k_scores_mfma(
    const float* __restrict__ embeds,    // [B][S][D]
    const float* __restrict__ mask,      // [B][S]
    const float* __restrict__ pos_table, // [132][D]
    const float* __restrict__ tok_mult,  // [1]
    const int*   __restrict__ rel_ids,   // [B][S]
    const _Float16* __restrict__ whi,    // [NKC][CT][64][8]
    float* __restrict__ partial,         // [B][NBLK][D]
    float* __restrict__ mblk,            // [B][NBLK]
    float* __restrict__ zblk)            // [B][NBLK]
{
    // exactly 80KB: W dbuf [0,32K), E ring [32K,80K); epilogue overlays [0,2K)
    __shared__ __align__(16) char smem[81920];
    auto Wslot = [&](int i) -> _Float16* { return (_Float16*)(smem + (i & 1) * 16384); };
    auto Eslot = [&](int i) -> float*    { int m = i % 3; return (float*)(smem + 32768 + m * 16384); };
    float* l_sh = (float*)(smem);            // 128 f
    float* w_sh = (float*)(smem + 512);      // 128 f
    float* red2 = (float*)(smem + 1024);     // 2 f
    float* zred = (float*)(smem + 1032);     // 2 f

    const int t  = threadIdx.x;
    const int wv = t >> 6;      // wave 0..3
    const int l  = t & 63;
    const int lr = l & 15;      // token within set / output col
    const int lg = l >> 4;      // k-group

    const int b   = blockIdx.x >> 4;     // 16 blocks of 128 tokens per batch
    const int blk = blockIdx.x & 15;
    const int s0  = blk * 128;

    const float tm = tok_mult[0];

    const float* prow[2];
    #pragma unroll
    for (int st = 0; st < 2; st++) {
        const int tok = s0 + wv * 32 + st * 16 + lr;
        prow[st] = pos_table + (size_t)(rel_ids[b * Ss + tok] + HC) * Dd;
    }

    f32x4 acc[CT][2];
    #pragma unroll
    for (int ct = 0; ct < CT; ct++)
        #pragma unroll
        for (int st = 0; st < 2; st++) acc[ct][st] = (f32x4){0.f, 0.f, 0.f, 0.f};

    // pos prefetch registers (one kc ahead): 4 gather loads (cache-hot rows)
    f32x4 p0[2], p1[2];
    auto loadP = [&](int kc) {
        const int k0 = kc * 32 + lg * 8;
        #pragma unroll
        for (int st = 0; st < 2; st++) {
            p0[st] = *(const f32x4*)(prow[st] + k0);
            p1[st] = *(const f32x4*)(prow[st] + k0 + 4);
        }
    };

    // stage one 16KB W_hi chunk: 16 wave-chunks of 1KB (4 insts/thread)
    auto stageW = [&](int kc, _Float16* dst) {
        const _Float16* src = whi + (size_t)kc * 8192;
        #pragma unroll
        for (int i = 0; i < 4; i++) {
            const int off = (i * 4 + wv) << 9;   // elems; 1KB chunks
            __builtin_amdgcn_global_load_lds(
                (const __attribute__((address_space(1))) void*)(src + off + l * 8),
                (__attribute__((address_space(3))) void*)(dst + off),
                16, 0, 0);
        }
    };

    // stage one 16KB e tile [128 rows][8 16B-units], XOR-swizzled:
    // LDS unit j = row*8 + u holds e[row][u ^ (row&7)] (16B units).
    auto stageE = [&](int kc, float* dst) {
        const float* ebase = embeds + ((size_t)b * Ss + s0) * Dd + kc * 32;
        #pragma unroll
        for (int i = 0; i < 4; i++) {
            const int jbase = i * 256 + wv * 64;     // unit idx of lane 0
            const int j = jbase + l;                 // this lane's unit
            const int row = j >> 3, u = j & 7;
            const float* src = ebase + (size_t)row * Dd + ((u ^ (row & 7)) << 2);
            __builtin_amdgcn_global_load_lds(
                (const __attribute__((address_space(1))) void*)src,
                (__attribute__((address_space(3))) void*)(dst + jbase * 4),
                16, 0, 0);
        }
    };

    // prologue: queue = [W(0):4, E(0):4, E(1):4, P(0):4]
    stageW(0, Wslot(0));
    stageE(0, Eslot(0));
    stageE(1, Eslot(1));
    loadP(0);
    asm volatile("s_waitcnt vmcnt(8)" ::: "memory");  // W(0)+E(0) landed
    __builtin_amdgcn_s_barrier();

    for (int kc = 0; kc < NKC; kc++) {
        if (kc + 1 < NKC) stageW(kc + 1, Wslot(kc + 1));   // 4 DMA
        if (kc + 2 < NKC) stageE(kc + 2, Eslot(kc + 2));   // 4 DMA

        // build B frags: e from swizzled LDS ring slot kc, pos from p regs
        // (first use of p regs auto-waits; that also drains E(kc+1))
        f16x8 bh[2], bl[2];
        {
            const float* es = Eslot(kc);
            #pragma unroll
            for (int st = 0; st < 2; st++) {
                const int row = wv * 32 + st * 16 + lr;
                const int sw  = row & 7;
                const f32x4 x0 = *(const f32x4*)(es + row * 32 + (((lg << 1)    ) ^ sw) * 4);
                const f32x4 x1 = *(const f32x4*)(es + row * 32 + (((lg << 1) | 1) ^ sw) * 4);
                float e[8], p[8];
                *(f32x4*)&e[0] = x0;     *(f32x4*)&e[4] = x1;
                *(f32x4*)&p[0] = p0[st]; *(f32x4*)&p[4] = p1[st];
                #pragma unroll
                for (int i = 0; i < 8; i++) {
                    const float x = fmaf(tm, e[i], p[i]);
                    const _Float16 h = (_Float16)x;
                    bh[st][i] = h;
                    bl[st][i] = (_Float16)(x - (float)h);
                }
            }
        }
        if (kc + 1 < NKC) loadP(kc + 1);   // 4 gathers; stay in flight

        const _Float16* base = Wslot(kc);
        __builtin_amdgcn_s_setprio(1);
        #pragma unroll
        for (int ct = 0; ct < CT; ct++) {
            const f16x8 ah = *(const f16x8*)(base + ct * 512 + l * 8);
            // dep-break order: same-acc MFMAs are 2 apart, not back-to-back
            acc[ct][0] = __builtin_amdgcn_mfma_f32_16x16x32_f16(ah, bh[0], acc[ct][0], 0, 0, 0);
            acc[ct][1] = __builtin_amdgcn_mfma_f32_16x16x32_f16(ah, bh[1], acc[ct][1], 0, 0, 0);
            acc[ct][0] = __builtin_amdgcn_mfma_f32_16x16x32_f16(ah, bl[0], acc[ct][0], 0, 0, 0);
            acc[ct][1] = __builtin_amdgcn_mfma_f32_16x16x32_f16(ah, bl[1], acc[ct][1], 0, 0, 0);
        }
        __builtin_amdgcn_s_setprio(0);
        // end drain: wait W(kc+1) only; E(kc+2)+P(kc+1) stay in flight
        if (kc < NKC - 2)       { asm volatile("s_waitcnt vmcnt(8)" ::: "memory"); }
        else if (kc == NKC - 2) { asm volatile("s_waitcnt vmcnt(4)" ::: "memory"); }
        else                    { asm volatile("s_waitcnt vmcnt(0)" ::: "memory"); }
        __builtin_amdgcn_s_barrier();
    }

    // masked logit per token -> LDS (overlay region; W/E buffers are dead)
    #pragma unroll
    for (int st = 0; st < 2; st++) {
        float mx = acc[0][st][0];
        #pragma unroll
        for (int ct = 0; ct < CT; ct++)
            #pragma unroll
            for (int r = 0; r < 4; r++) mx = fmaxf(mx, acc[ct][st][r]);
        mx = fmaxf(mx, __shfl_xor(mx, 16));
        mx = fmaxf(mx, __shfl_xor(mx, 32));
        if (lg == 0) {
            const int si = wv * 32 + st * 16 + lr;   // token within block
            const int s  = s0 + si;
            const float mk = mask[b * Ss + s];
            l_sh[si] = mx * mk + (mk - 1.0f) * NEGV;
        }
    }
    __syncthreads();

    // block max M_b over the 128 logits
    if (t < 128) {
        float v = l_sh[t];
        #pragma unroll
        for (int o = 32; o >= 1; o >>= 1) v = fmaxf(v, __shfl_xor(v, o));
        if ((t & 63) == 0) red2[t >> 6] = v;
    }
    __syncthreads();
    const float Mb = fmaxf(red2[0], red2[1]);
    if (t < 128) w_sh[t] = expf(l_sh[t] - Mb);
    __syncthreads();
    if (t < 128) {
        float z = w_sh[t];
        #pragma unroll
        for (int o = 32; o >= 1; o >>= 1) z += __shfl_xor(z, o);
        if ((t & 63) == 0) zred[t >> 6] = z;
    }
    __syncthreads();

    // block-local ctx partial: P[d] = sum_s w_sh[s] * e[s0+s][d]  (L2-hot)
    {
        const float* eb = embeds + ((size_t)b * Ss + s0) * Dd + t * 4;
        f32x4 ca = (f32x4){0.f, 0.f, 0.f, 0.f};
        #pragma unroll 8
        for (int s = 0; s < 128; s++) {
            const float wgt = w_sh[s];
            const f32x4 ev = *(const f32x4*)(eb + (size_t)s * Dd);
            ca[0] = fmaf(wgt, ev[0], ca[0]);
            ca[1] = fmaf(wgt, ev[1], ca[1]);
            ca[2] = fmaf(wgt, ev[2], ca[2]);
            ca[3] = fmaf(wgt, ev[3], ca[3]);
        }
        *(f32x4*)(partial + ((size_t)(b * NBLK + blk)) * Dd + t * 4) = ca;
        if (t == 0) {
            mblk[b * NBLK + blk] = Mb;
            zblk[b * NBLK + blk] = zred[0] + zred[1];
        }
    }
}

// ------- Pass 2: global flash combine + tok_diag (parallel over d) -------
__global__ __launch_bounds__(256) void k_finish(
    const float* __restrict__ mblk, const float* __restrict__ zblk,
    const float* __restrict__ partial, const float* __restrict__ tok_diag,
    float* __restrict__ out)
{
    __shared__ float cf[NBLK];
    const int b  = blockIdx.x >> 2;      // batch
    const int dq = blockIdx.x & 3;       // d quarter (256 floats)
    const int t  = threadIdx.x;

    if (t < 64) {
        const float mv = (t < NBLK) ? mblk[b * NBLK + t] : -3.4e38f;
        float M = mv;
        #pragma unroll
        for (int o = 32; o >= 1; o >>= 1) M = fmaxf(M, __shfl_xor(M, o));
        const float zv = (t < NBLK) ? zblk[b * NBLK + t] * expf(mv - M) : 0.f;
        float Z = zv;
        #pragma unroll
        for (int o = 32; o >= 1; o >>= 1) Z += __shfl_xor(Z, o);
        if (t < NBLK) cf[t] = expf(mv - M) / Z;
    }
    __syncthreads();

    const int d = dq * 256 + t;          // one float per thread, coalesced
    float a = 0.f;
    #pragma unroll
    for (int j = 0; j < NBLK; j++)
        a = fmaf(cf[j], partial[((size_t)(b * NBLK + j)) * Dd + d], a);
    out[(size_t)b * Dd + d] = a * tok_diag[d];
}

extern "C" void kernel_launch(void* const* d_in, const int* in_sizes, int n_in,
                              void* d_out, int out_size, void* d_ws, size_t ws_size,
                              hipStream_t stream) {
    const float* embeds    = (const float*)d_in[0];
    const float* mask      = (const float*)d_in[1];
    const float* latent    = (const float*)d_in[2];
    const float* att_diag  = (const float*)d_in[3];
    const float* tok_diag  = (const float*)d_in[4];
    const float* pos_table = (const float*)d_in[5];
    const float* tok_mult  = (const float*)d_in[6];
    const int*   rel_ids   = (const int*)d_in[7];
    float* out = (float*)d_out;

    char* ws = (char*)d_ws;
    _Float16* whi    = (_Float16*)(ws);              // 512 KB
    float*    partial= (float*)(ws + 524288);        // 2 MB
    float*    mblk   = (float*)(ws + 2621440);       // 2 KB
    float*    zblk   = (float*)(ws + 2623488);       // 2 KB

    k_prep_w<<<(Cc * Dd) / 256, 256, 0, stream>>>(latent, att_diag, whi);
    k_scores_mfma<<<Bb * NBLK, 256, 0, stream>>>(
        embeds, mask, pos_table, tok_mult, rel_ids, whi, partial, mblk, zblk);
    k_finish<<<Bb * 4, 256, 0, stream>>>(mblk, zblk, partial, tok_diag, out);
}

// Round 25
// 99.617 us; speedup vs baseline: 1.6396x; 1.1476x over previous
//
#include <hip/hip_runtime.h>
#include <hip/hip_bf16.h>

// B=32, S=2048, D=1024, C=256
//   top[b,s] = max_c sum_d (latent[c,d]*att_diag[d]) * (tm*embeds[b,s,d] + pos_table[rel+64,d])
//   p = softmax_s(top*m + (m-1)*NEG);  ctx[b,d] = tok_diag[d] * sum_s embeds*p
//
// R25 = R22 (best, 113.3us) with the e-side hi/lo split REMOVED:
// pure fp16 x fp16 MFMA (W_hi * x_hi, x = tm*e + p). The e-split's error
// contribution was ~2^-22 relative (negligible vs W-rounding), but cost 2x
// MFMA + the sub/re-cvt build chain. Predicted absmax ~0.09 (thr 0.21).
// MFMA per kc per wave: 64 -> 32; build: 16 cvt (no sub+cvt).
// Everything else identical to R22: e staged via global_load_lds with
// XOR swizzle (3-deep ring), W dbuf, counted vmcnt, flash epilogue,
// parallel k_finish.
//
// ws: whi 512K | partial 2M | mblk 2K | zblk 2K

#define HC 64
#define NEGV 1000000000000.0f

constexpr int Bb = 32, Ss = 2048, Dd = 1024, Cc = 256;
constexpr int NKC = 32;                 // k-chunks of 32
constexpr int CT = Cc / 16;             // 16 c-tiles
constexpr int NBLK = 16;                // 128-token blocks per batch

typedef _Float16 f16x8 __attribute__((ext_vector_type(8)));
typedef float    f32x4 __attribute__((ext_vector_type(4)));

// ---------------- Pass 0: W_hi -> per-kc fragment chunks ----------
// layout: whi[kc][ct][lane][8] (16KB/kc)
// A-frag map: lane = (c%16) + 16*g holds A[c][k = kc*32 + 8g + i]
__global__ __launch_bounds__(256) void k_prep_w(
    const float* __restrict__ latent, const float* __restrict__ att_diag,
    _Float16* __restrict__ whi)
{
    const int idx = blockIdx.x * 256 + threadIdx.x;   // c*Dd + k
    const int c = idx >> 10, k = idx & 1023;
    const float wv = latent[idx] * att_diag[k];
    const int kc = k >> 5, g = (k >> 3) & 3, i = k & 7;
    const int lane = (c & 15) + 16 * g, ct = c >> 4;
    whi[(size_t)kc * 8192 + (size_t)ct * 512 + lane * 8 + i] = (_Float16)wv;
}

// ------- Pass 1: scores via MFMA, block max/sumexp, flash ctx partial -----
__global__ __launch_bounds__(256, 2) void k_scores_mfma(
    const float* __restrict__ embeds,    // [B][S][D]
    const float* __restrict__ mask,      // [B][S]
    const float* __restrict__ pos_table, // [132][D]
    const float* __restrict__ tok_mult,  // [1]
    const int*   __restrict__ rel_ids,   // [B][S]
    const _Float16* __restrict__ whi,    // [NKC][CT][64][8]
    float* __restrict__ partial,         // [B][NBLK][D]
    float* __restrict__ mblk,            // [B][NBLK]
    float* __restrict__ zblk)            // [B][NBLK]
{
    // exactly 80KB: W dbuf [0,32K), E ring [32K,80K); epilogue overlays [0,2K)
    __shared__ __align__(16) char smem[81920];
    auto Wslot = [&](int i) -> _Float16* { return (_Float16*)(smem + (i & 1) * 16384); };
    auto Eslot = [&](int i) -> float*    { int m = i % 3; return (float*)(smem + 32768 + m * 16384); };
    float* l_sh = (float*)(smem);            // 128 f
    float* w_sh = (float*)(smem + 512);      // 128 f
    float* red2 = (float*)(smem + 1024);     // 2 f
    float* zred = (float*)(smem + 1032);     // 2 f

    const int t  = threadIdx.x;
    const int wv = t >> 6;      // wave 0..3
    const int l  = t & 63;
    const int lr = l & 15;      // token within set / output col
    const int lg = l >> 4;      // k-group

    const int b   = blockIdx.x >> 4;     // 16 blocks of 128 tokens per batch
    const int blk = blockIdx.x & 15;
    const int s0  = blk * 128;

    const float tm = tok_mult[0];

    const float* prow[2];
    #pragma unroll
    for (int st = 0; st < 2; st++) {
        const int tok = s0 + wv * 32 + st * 16 + lr;
        prow[st] = pos_table + (size_t)(rel_ids[b * Ss + tok] + HC) * Dd;
    }

    f32x4 acc[CT][2];
    #pragma unroll
    for (int ct = 0; ct < CT; ct++)
        #pragma unroll
        for (int st = 0; st < 2; st++) acc[ct][st] = (f32x4){0.f, 0.f, 0.f, 0.f};

    // pos prefetch registers (one kc ahead): 4 gather loads (cache-hot rows)
    f32x4 p0[2], p1[2];
    auto loadP = [&](int kc) {
        const int k0 = kc * 32 + lg * 8;
        #pragma unroll
        for (int st = 0; st < 2; st++) {
            p0[st] = *(const f32x4*)(prow[st] + k0);
            p1[st] = *(const f32x4*)(prow[st] + k0 + 4);
        }
    };

    // stage one 16KB W_hi chunk: 16 wave-chunks of 1KB (4 insts/thread)
    auto stageW = [&](int kc, _Float16* dst) {
        const _Float16* src = whi + (size_t)kc * 8192;
        #pragma unroll
        for (int i = 0; i < 4; i++) {
            const int off = (i * 4 + wv) << 9;   // elems; 1KB chunks
            __builtin_amdgcn_global_load_lds(
                (const __attribute__((address_space(1))) void*)(src + off + l * 8),
                (__attribute__((address_space(3))) void*)(dst + off),
                16, 0, 0);
        }
    };

    // stage one 16KB e tile [128 rows][8 16B-units], XOR-swizzled:
    // LDS unit j = row*8 + u holds e[row][u ^ (row&7)] (16B units).
    auto stageE = [&](int kc, float* dst) {
        const float* ebase = embeds + ((size_t)b * Ss + s0) * Dd + kc * 32;
        #pragma unroll
        for (int i = 0; i < 4; i++) {
            const int jbase = i * 256 + wv * 64;     // unit idx of lane 0
            const int j = jbase + l;                 // this lane's unit
            const int row = j >> 3, u = j & 7;
            const float* src = ebase + (size_t)row * Dd + ((u ^ (row & 7)) << 2);
            __builtin_amdgcn_global_load_lds(
                (const __attribute__((address_space(1))) void*)src,
                (__attribute__((address_space(3))) void*)(dst + jbase * 4),
                16, 0, 0);
        }
    };

    // prologue: queue = [W(0):4, E(0):4, E(1):4, P(0):4]
    stageW(0, Wslot(0));
    stageE(0, Eslot(0));
    stageE(1, Eslot(1));
    loadP(0);
    asm volatile("s_waitcnt vmcnt(8)" ::: "memory");  // W(0)+E(0) landed
    __builtin_amdgcn_s_barrier();

    for (int kc = 0; kc < NKC; kc++) {
        if (kc + 1 < NKC) stageW(kc + 1, Wslot(kc + 1));   // 4 DMA
        if (kc + 2 < NKC) stageE(kc + 2, Eslot(kc + 2));   // 4 DMA

        // build B frags: e from swizzled LDS ring slot kc, pos from p regs
        // (first use of p regs auto-waits; that also drains E(kc+1))
        f16x8 bh[2];
        {
            const float* es = Eslot(kc);
            #pragma unroll
            for (int st = 0; st < 2; st++) {
                const int row = wv * 32 + st * 16 + lr;
                const int sw  = row & 7;
                const f32x4 x0 = *(const f32x4*)(es + row * 32 + (((lg << 1)    ) ^ sw) * 4);
                const f32x4 x1 = *(const f32x4*)(es + row * 32 + (((lg << 1) | 1) ^ sw) * 4);
                float e[8], p[8];
                *(f32x4*)&e[0] = x0;     *(f32x4*)&e[4] = x1;
                *(f32x4*)&p[0] = p0[st]; *(f32x4*)&p[4] = p1[st];
                #pragma unroll
                for (int i = 0; i < 8; i++)
                    bh[st][i] = (_Float16)fmaf(tm, e[i], p[i]);
            }
        }
        if (kc + 1 < NKC) loadP(kc + 1);   // 4 gathers; stay in flight

        const _Float16* base = Wslot(kc);
        #pragma unroll
        for (int ct = 0; ct < CT; ct++) {
            const f16x8 ah = *(const f16x8*)(base + ct * 512 + l * 8);
            acc[ct][0] = __builtin_amdgcn_mfma_f32_16x16x32_f16(ah, bh[0], acc[ct][0], 0, 0, 0);
            acc[ct][1] = __builtin_amdgcn_mfma_f32_16x16x32_f16(ah, bh[1], acc[ct][1], 0, 0, 0);
        }
        // end drain: wait W(kc+1) only; E(kc+2)+P(kc+1) stay in flight
        if (kc < NKC - 2)       { asm volatile("s_waitcnt vmcnt(8)" ::: "memory"); }
        else if (kc == NKC - 2) { asm volatile("s_waitcnt vmcnt(4)" ::: "memory"); }
        else                    { asm volatile("s_waitcnt vmcnt(0)" ::: "memory"); }
        __builtin_amdgcn_s_barrier();
    }

    // masked logit per token -> LDS (overlay region; W/E buffers are dead)
    #pragma unroll
    for (int st = 0; st < 2; st++) {
        float mx = acc[0][st][0];
        #pragma unroll
        for (int ct = 0; ct < CT; ct++)
            #pragma unroll
            for (int r = 0; r < 4; r++) mx = fmaxf(mx, acc[ct][st][r]);
        mx = fmaxf(mx, __shfl_xor(mx, 16));
        mx = fmaxf(mx, __shfl_xor(mx, 32));
        if (lg == 0) {
            const int si = wv * 32 + st * 16 + lr;   // token within block
            const int s  = s0 + si;
            const float mk = mask[b * Ss + s];
            l_sh[si] = mx * mk + (mk - 1.0f) * NEGV;
        }
    }
    __syncthreads();

    // block max M_b over the 128 logits
    if (t < 128) {
        float v = l_sh[t];
        #pragma unroll
        for (int o = 32; o >= 1; o >>= 1) v = fmaxf(v, __shfl_xor(v, o));
        if ((t & 63) == 0) red2[t >> 6] = v;
    }
    __syncthreads();
    const float Mb = fmaxf(red2[0], red2[1]);
    if (t < 128) w_sh[t] = expf(l_sh[t] - Mb);
    __syncthreads();
    if (t < 128) {
        float z = w_sh[t];
        #pragma unroll
        for (int o = 32; o >= 1; o >>= 1) z += __shfl_xor(z, o);
        if ((t & 63) == 0) zred[t >> 6] = z;
    }
    __syncthreads();

    // block-local ctx partial: P[d] = sum_s w_sh[s] * e[s0+s][d]  (L2-hot)
    {
        const float* eb = embeds + ((size_t)b * Ss + s0) * Dd + t * 4;
        f32x4 ca = (f32x4){0.f, 0.f, 0.f, 0.f};
        #pragma unroll 8
        for (int s = 0; s < 128; s++) {
            const float wgt = w_sh[s];
            const f32x4 ev = *(const f32x4*)(eb + (size_t)s * Dd);
            ca[0] = fmaf(wgt, ev[0], ca[0]);
            ca[1] = fmaf(wgt, ev[1], ca[1]);
            ca[2] = fmaf(wgt, ev[2], ca[2]);
            ca[3] = fmaf(wgt, ev[3], ca[3]);
        }
        *(f32x4*)(partial + ((size_t)(b * NBLK + blk)) * Dd + t * 4) = ca;
        if (t == 0) {
            mblk[b * NBLK + blk] = Mb;
            zblk[b * NBLK + blk] = zred[0] + zred[1];
        }
    }
}

// ------- Pass 2: global flash combine + tok_diag (parallel over d) -------
__global__ __launch_bounds__(256) void k_finish(
    const float* __restrict__ mblk, const float* __restrict__ zblk,
    const float* __restrict__ partial, const float* __restrict__ tok_diag,
    float* __restrict__ out)
{
    __shared__ float cf[NBLK];
    const int b  = blockIdx.x >> 2;      // batch
    const int dq = blockIdx.x & 3;       // d quarter (256 floats)
    const int t  = threadIdx.x;

    if (t < 64) {
        const float mv = (t < NBLK) ? mblk[b * NBLK + t] : -3.4e38f;
        float M = mv;
        #pragma unroll
        for (int o = 32; o >= 1; o >>= 1) M = fmaxf(M, __shfl_xor(M, o));
        const float zv = (t < NBLK) ? zblk[b * NBLK + t] * expf(mv - M) : 0.f;
        float Z = zv;
        #pragma unroll
        for (int o = 32; o >= 1; o >>= 1) Z += __shfl_xor(Z, o);
        if (t < NBLK) cf[t] = expf(mv - M) / Z;
    }
    __syncthreads();

    const int d = dq * 256 + t;          // one float per thread, coalesced
    float a = 0.f;
    #pragma unroll
    for (int j = 0; j < NBLK; j++)
        a = fmaf(cf[j], partial[((size_t)(b * NBLK + j)) * Dd + d], a);
    out[(size_t)b * Dd + d] = a * tok_diag[d];
}

extern "C" void kernel_launch(void* const* d_in, const int* in_sizes, int n_in,
                              void* d_out, int out_size, void* d_ws, size_t ws_size,
                              hipStream_t stream) {
    const float* embeds    = (const float*)d_in[0];
    const float* mask      = (const float*)d_in[1];
    const float* latent    = (const float*)d_in[2];
    const float* att_diag  = (const float*)d_in[3];
    const float* tok_diag  = (const float*)d_in[4];
    const float* pos_table = (const float*)d_in[5];
    const float* tok_mult  = (const float*)d_in[6];
    const int*   rel_ids   = (const int*)d_in[7];
    float* out = (float*)d_out;

    char* ws = (char*)d_ws;
    _Float16* whi    = (_Float16*)(ws);              // 512 KB
    float*    partial= (float*)(ws + 524288);        // 2 MB
    float*    mblk   = (float*)(ws + 2621440);       // 2 KB
    float*    zblk   = (float*)(ws + 2623488);       // 2 KB

    k_prep_w<<<(Cc * Dd) / 256, 256, 0, stream>>>(latent, att_diag, whi);
    k_scores_mfma<<<Bb * NBLK, 256, 0, stream>>>(
        embeds, mask, pos_table, tok_mult, rel_ids, whi, partial, mblk, zblk);
    k_finish<<<Bb * 4, 256, 0, stream>>>(mblk, zblk, partial, tok_diag, out);
}